// Round 8
// baseline (255.608 us; speedup 1.0000x reference)
//
#include <hip/hip_runtime.h>
#include <cmath>

#define GAMMA 0.9865f
#define L2G   -0.01960905f   // log2(0.9865)
#define BATCH 8
#define SEQ   4000
#define CSUP  25
#define GSUP  32
#define RPG   125            // rows per superchunk = 5*CSUP

typedef _Float16 half8 __attribute__((ext_vector_type(8)));
typedef _Float16 half4 __attribute__((ext_vector_type(4)));
typedef float    floatx4 __attribute__((ext_vector_type(4)));

__device__ __forceinline__ float gpow(float e) { return exp2f(e * L2G); }  // GAMMA^e

// ---------------- Kernel 0: convert W -> MFMA-fragment layout fp16.
// Wf[op][((dt*16 + nt)*64 + lane)*8 + z] = W[k][n], k = dt*32 + q8(lane) + z, n = nt*16 + (lane&15).
// qkv waves then load B-fragments directly from global (L2-resident), no LDS staging for W.
__global__ __launch_bounds__(256) void wt_convert(
    const float* __restrict__ Wq, const float* __restrict__ Wk, const float* __restrict__ Wv,
    _Float16* __restrict__ Wf) {
    int u = blockIdx.x * 256 + threadIdx.x;           // 3*8192 = 24576
    int op = u >> 13, rem = u & 8191;
    int dt = rem >> 10, nt = (rem >> 6) & 15, lane = rem & 63;
    int ln = lane & 15, q8 = (lane >> 4) << 3;
    const float* W = (op == 0) ? Wq : (op == 1) ? Wk : Wv;
    int n = nt * 16 + ln, k = dt * 32 + q8;
    half8 h;
#pragma unroll
    for (int z = 0; z < 8; ++z) h[z] = (_Float16)W[(k + z) * 256 + n];
    *(half8*)&Wf[(size_t)op * 65536 + (size_t)(((dt * 16 + nt) * 64 + lane) << 3)] = h;
}

// ---------------- Kernel 1: QKV projection, fp16 MFMA.  dst = x @ W  (M=32000,N=256,K=256)
// v7: X LDS double-buffer only (20,480 B); W fragments register-prefetched direct from
// global Wf (L2-hit) -> W loads float across barriers, no vmcnt(0)-coupled ds_write for W.
__global__ __launch_bounds__(256, 2) void qkv_gemm_f16(
    const float* __restrict__ xq, const float* __restrict__ xk, const float* __restrict__ xv,
    const _Float16* __restrict__ WfAll,
    _Float16* __restrict__ Qb, _Float16* __restrict__ Kb, _Float16* __restrict__ Vb) {
    int op = blockIdx.y;
    const float* x = (op == 0) ? xq : (op == 1) ? xk : xv;
    const _Float16* Wf = WfAll + (size_t)op * 65536;
    _Float16* dst = (op == 0) ? Qb : (op == 1) ? Kb : Vb;

    __shared__ _Float16 Xs[2][128][40];   // 20,480 B

    int t = threadIdx.x;
    int lane = t & 63, wave = t >> 6;
    int ln = lane & 15, q8 = (lane >> 4) << 3, q4 = (lane >> 4) << 2;
    int row0 = blockIdx.x * 128;

    int xm = t >> 3, xk_ = (t & 7) << 2;   // X stage: m = xm + i*32, cols xk_..xk_+3

    floatx4 acc[8][4] = {};
    floatx4 xn[4];
    half8 wc[4], wn[4];

    auto loadX = [&](int dt) {
        int k0 = dt * 32;
#pragma unroll
        for (int i = 0; i < 4; ++i)
            xn[i] = *(const floatx4*)&x[(size_t)(row0 + xm + i * 32) * 256 + k0 + xk_];
    };
    auto loadW = [&](int dt, half8* w) {
#pragma unroll
        for (int ni = 0; ni < 4; ++ni)
            w[ni] = *(const half8*)&Wf[(size_t)(((dt * 16 + wave * 4 + ni) * 64 + lane) << 3)];
    };
    auto writeX = [&](int bf) {
#pragma unroll
        for (int i = 0; i < 4; ++i) {
            half4 h; h[0] = (_Float16)xn[i][0]; h[1] = (_Float16)xn[i][1];
            h[2] = (_Float16)xn[i][2]; h[3] = (_Float16)xn[i][3];
            *(half4*)&Xs[bf][xm + i * 32][xk_] = h;
        }
    };

    loadX(0); loadW(0, wc); writeX(0);
    int cur = 0;
    for (int dt = 0; dt < 8; ++dt) {
        __syncthreads();
        if (dt < 7) { loadX(dt + 1); loadW(dt + 1, wn); }
        half8 af[8];
#pragma unroll
        for (int mi = 0; mi < 8; ++mi) af[mi] = *(const half8*)&Xs[cur][mi * 16 + ln][q8];
#pragma unroll
        for (int ni = 0; ni < 4; ++ni)
#pragma unroll
            for (int mi = 0; mi < 8; ++mi)
                acc[mi][ni] = __builtin_amdgcn_mfma_f32_16x16x32_f16(af[mi], wc[ni], acc[mi][ni], 0, 0, 0);
        if (dt < 7) {
            writeX(cur ^ 1);
#pragma unroll
            for (int ni = 0; ni < 4; ++ni) wc[ni] = wn[ni];
            cur ^= 1;
        }
    }
#pragma unroll
    for (int mi = 0; mi < 8; ++mi)
#pragma unroll
        for (int ni = 0; ni < 4; ++ni)
#pragma unroll
            for (int r = 0; r < 4; ++r) {
                int row = row0 + mi * 16 + q4 + r;
                int col = (wave * 4 + ni) * 16 + ln;
                dst[(size_t)row * 256 + col] = (_Float16)acc[mi][ni][r];
            }
}

// ---------------- Kernel 1b: V transpose into padded VT[b][e][g][128] (fp16, zeros for cp>=125).
__global__ __launch_bounds__(256) void vt_transpose(
    const _Float16* __restrict__ Vb, _Float16* __restrict__ VT) {
    int es = blockIdx.x, g = blockIdx.y, b = blockIdx.z;
    int t = threadIdx.x;
    __shared__ __align__(16) _Float16 Ls[64 * 136];
    // logical Ls[e][cp], physical: e*136 + (((cp>>3) ^ (e>>3))<<3) + (cp&7)
#pragma unroll
    for (int i = 0; i < 4; ++i) {
        int idx = t + i * 256;
        int cp = idx >> 3, eg = idx & 7;
        half8 v = {};
        if (cp < 125)
            v = *(const half8*)&Vb[((size_t)b * SEQ + g * RPG + cp) * 256 + es * 64 + eg * 8];
        int cpg = cp >> 3, c7 = cp & 7;
#pragma unroll
        for (int z = 0; z < 8; ++z) {
            int e = eg * 8 + z;
            Ls[e * 136 + ((cpg ^ (e >> 3)) << 3) + c7] = v[z];
        }
    }
    __syncthreads();
#pragma unroll
    for (int jj = 0; jj < 4; ++jj) {
        int ee = jj * 16 + (t >> 4);
        int cpg = t & 15;
        half8 h = *(const half8*)&Ls[ee * 136 + ((cpg ^ (ee >> 3)) << 3)];
        *(half8*)&VT[(((size_t)b * 256 + es * 64 + ee) * 32 + g) * 128 + cpg * 8] = h;
    }
}

// ---------------- Kernel 2: chunk states via MFMA (R7-verified: transposed swizzled staging).
__global__ __launch_bounds__(256, 2) void chunk_states_mfma(
    const _Float16* __restrict__ Kb, const _Float16* __restrict__ Vb,
    _Float16* __restrict__ Wh) {
    int lin = blockIdx.x + 2 * (blockIdx.y + 32 * blockIdx.z);   // 0..511
    int swz = (lin & 7) * 64 + (lin >> 3);
    int eh = swz & 1, g = (swz >> 1) & 31, b = swz >> 6;

    int t = threadIdx.x, lane = t & 63, wave = t >> 6;
    int ln = lane & 15, q8 = (lane >> 4) << 3, q4 = (lane >> 4) << 2;
    __shared__ __align__(16) _Float16 VsT[128 * 40];   // [e][r]
    __shared__ __align__(16) _Float16 KsT[256 * 40];   // [d][r]
    size_t base_row = (size_t)b * SEQ + g * RPG;
    floatx4 acc[8][4] = {};
    int rb = q8 >> 3;                                  // k-block index 0..3
    for (int kt = 0; kt < 4; ++kt) {
        int r0 = kt * 32;
#pragma unroll
        for (int i = 0; i < 2; ++i) {          // V^T stage with alpha: 8 e's at fixed r
            int idx = t + i * 256;
            int r = idx >> 4, e8 = (idx & 15) << 3;
            half8 v = {};
            if (r0 + r < RPG) {
                v = *(const half8*)&Vb[(base_row + r0 + r) * 256 + eh * 128 + e8];
                int mloc = (r0 + r) / 5;
                float a = gpow((float)(149 - 6 * mloc));
#pragma unroll
                for (int z = 0; z < 8; ++z) v[z] = (_Float16)((float)v[z] * a);
            }
            int base = e8 * 40 + ((((r >> 3) ^ ((e8 >> 3) & 3))) << 3) + (r & 7);
#pragma unroll
            for (int z = 0; z < 8; ++z) VsT[base + z * 40] = v[z];
        }
#pragma unroll
        for (int i = 0; i < 4; ++i) {          // K^T stage: 8 d's at fixed r
            int idx = t + i * 256;
            int r = idx >> 5, d8 = (idx & 31) << 3;
            half8 v = {};
            if (r0 + r < RPG) v = *(const half8*)&Kb[(base_row + r0 + r) * 256 + d8];
            int base = d8 * 40 + ((((r >> 3) ^ ((d8 >> 3) & 3))) << 3) + (r & 7);
#pragma unroll
            for (int z = 0; z < 8; ++z) KsT[base + z * 40] = v[z];
        }
        __syncthreads();
        half8 Af[8], Bf[4];
#pragma unroll
        for (int mi = 0; mi < 8; ++mi) {
            int e = mi * 16 + ln;
            Af[mi] = *(const half8*)&VsT[e * 40 + ((rb ^ ((e >> 3) & 3)) << 3)];
        }
#pragma unroll
        for (int ni = 0; ni < 4; ++ni) {
            int d = wave * 64 + ni * 16 + ln;
            Bf[ni] = *(const half8*)&KsT[d * 40 + ((rb ^ ((d >> 3) & 3)) << 3)];
        }
#pragma unroll
        for (int mi = 0; mi < 8; ++mi)
#pragma unroll
            for (int ni = 0; ni < 4; ++ni)
                acc[mi][ni] = __builtin_amdgcn_mfma_f32_16x16x32_f16(Af[mi], Bf[ni], acc[mi][ni], 0, 0, 0);
        __syncthreads();
    }
    size_t ob = ((size_t)(g * 8 + b)) << 16;
#pragma unroll
    for (int mi = 0; mi < 8; ++mi)
#pragma unroll
        for (int ni = 0; ni < 4; ++ni)
#pragma unroll
            for (int r = 0; r < 4; ++r) {
                int e = eh * 128 + mi * 16 + q4 + r;
                int d = wave * 64 + ni * 16 + ln;
                Wh[ob + (size_t)e * 256 + d] = (_Float16)acc[mi][ni][r];
            }
}

// ---------------- Kernel 3: exclusive scan over g (fp16 in/out, fp32 accum)
__global__ __launch_bounds__(256) void state_scan(
    const _Float16* __restrict__ Wh, _Float16* __restrict__ SprevT) {
    int t = blockIdx.x * 256 + threadIdx.x;   // 131072 threads
    int b = t >> 14;
    int idx = (t & 16383) << 2;               // 4 consecutive halves
    const float gF = gpow(150.0f);
    float s[4] = {};
    half4 w = *(const half4*)&Wh[(((size_t)b) << 16) + idx];
    for (int g = 0; g < GSUP; ++g) {
        size_t o = (((size_t)(g * 8 + b)) << 16) + idx;
        half4 wn = {};
        if (g < GSUP - 1) wn = *(const half4*)&Wh[o + (8ull << 16)];
        half4 sv;
#pragma unroll
        for (int z = 0; z < 4; ++z) { sv[z] = (_Float16)s[z]; s[z] = (float)w[z] + gF * s[z]; }
        *(half4*)&SprevT[o] = sv;
        w = wn;
    }
}

// ---------------- Kernel 4: intra score matrices, pre-scaled by gamma^(q-p).
__global__ __launch_bounds__(256) void intra_sc(
    const _Float16* __restrict__ Qb, const _Float16* __restrict__ Kb, float* __restrict__ scw) {
    int b = blockIdx.y;
    int j = blockIdx.x * 4 + (threadIdx.x >> 6);
    int lane = threadIdx.x & 63;
    size_t base = ((size_t)b * SEQ + j * 5) * 256 + lane * 4;
    half4 qv[5], kv[5];
#pragma unroll
    for (int p = 0; p < 5; ++p) {
        qv[p] = *(const half4*)&Qb[base + p * 256];
        kv[p] = *(const half4*)&Kb[base + p * 256];
    }
#pragma unroll
    for (int p = 0; p < 5; ++p)
#pragma unroll
        for (int q = 0; q <= p; ++q) {
            float s = 0.f;
#pragma unroll
            for (int z = 0; z < 4; ++z) s += (float)qv[p][z] * (float)kv[q][z];
#pragma unroll
            for (int off = 32; off; off >>= 1) s += __shfl_xor(s, off, 64);
            if (lane == 0) scw[((size_t)b * 800 + j) * 25 + p * 5 + q] = s * gpow((float)(q - p));
        }
}

// ---------------- Kernel 5: cross + fused intra epilogue (R7-verified).
__global__ __launch_bounds__(512, 2) void cross_f16(
    const _Float16* __restrict__ Qb, const _Float16* __restrict__ Kb,
    const _Float16* __restrict__ VT, const _Float16* __restrict__ SprevT,
    const float* __restrict__ scw, float* __restrict__ out) {
    int lin = blockIdx.x + 4 * (blockIdx.y + 32 * blockIdx.z);   // 0..1023
    int swz = (lin & 7) * 128 + (lin >> 3);
    int eq = swz & 3, g = (swz >> 2) & 31, b = swz >> 7;
    int e0 = eq * 64;
    int t = threadIdx.x;
    int lane = t & 63, wave = t >> 6;          // 8 waves
    int ln = lane & 15, q8 = (lane >> 4) << 3, q4 = (lane >> 4) << 2;
    int mw = wave;                             // m-tile index 0..7

    __shared__ __align__(16) char smem[52224];
    _Float16* QsB  = (_Float16*)smem;              // [2][128][40] = 20480 B
    _Float16* KsB  = (_Float16*)(smem + 20480);    // [2][128][40] = 20480 B
    _Float16* SsB  = (_Float16*)(smem + 40960);    // [2][64][40]  = 10240 B
    _Float16* VsTB = (_Float16*)smem;              // [64][136] (phase 2)
    _Float16* PsB  = (_Float16*)(smem + 17408);    // [128][136] (phase 2)
#define QS(bf_, m_, k_)  QsB[(bf_) * 5120 + (m_) * 40 + (k_)]
#define KS(bf_, m_, k_)  KsB[(bf_) * 5120 + (m_) * 40 + (k_)]
#define SS(bf_, m_, k_)  SsB[(bf_) * 2560 + (m_) * 40 + (k_)]
#define PS(m_, k_)  PsB[(m_) * 136 + (k_)]
#define VST(m_, k_) VsTB[(m_) * 136 + (k_)]

    size_t kvbase = (size_t)b * SEQ + g * RPG;
    size_t sb = ((size_t)(g * 8 + b)) << 16;

    int qm = t >> 2, qk = (t & 3) << 3;   // staging: Q/K row 0..127, col chunk 0..3
    int vm = t >> 3, vc = t & 7;          // VT: row 0..63, chunks vc, vc+8

    floatx4 pacc[8] = {};
    floatx4 acc[4] = {};
    half8 qn, kn, sn;
    half8 vtp[2];

    auto loadNext = [&](int dt) {
        int d0 = dt * 32;
        half8 z = {};
        int qr = g * RPG + 5 + qm;
        qn = z;
        if (qm < 125 && qr < SEQ) qn = *(const half8*)&Qb[((size_t)b * SEQ + qr) * 256 + d0 + qk];
        kn = z;
        if (qm < 125) kn = *(const half8*)&Kb[(kvbase + qm) * 256 + d0 + qk];
        if (t < 256) sn = *(const half8*)&SprevT[sb + (size_t)(e0 + (t >> 2)) * 256 + d0 + qk];
    };
    auto writeBuf = [&](int bf) {
        *(half8*)&QS(bf, qm, qk) = qn;
        *(half8*)&KS(bf, qm, qk) = kn;
        if (t < 256) *(half8*)&SS(bf, t >> 2, qk) = sn;
    };

    loadNext(0); writeBuf(0);
    int cur = 0;
    for (int dt = 0; dt < 8; ++dt) {
        __syncthreads();
        if (dt < 7) loadNext(dt + 1);
        if (dt == 7) {
            size_t vtbase = (((size_t)b * 256 + e0 + vm) * 32 + g) * 128;
            vtp[0] = *(const half8*)&VT[vtbase + vc * 8];
            vtp[1] = *(const half8*)&VT[vtbase + (vc + 8) * 8];
        }
        half8 af = *(const half8*)&QS(cur, mw * 16 + ln, q8);
#pragma unroll
        for (int ci = 0; ci < 8; ++ci) {
            half8 bf = *(const half8*)&KS(cur, ci * 16 + ln, q8);
            pacc[ci] = __builtin_amdgcn_mfma_f32_16x16x32_f16(af, bf, pacc[ci], 0, 0, 0);
        }
#pragma unroll
        for (int ei = 0; ei < 4; ++ei) {
            half8 sf = *(const half8*)&SS(cur, ei * 16 + ln, q8);
            acc[ei] = __builtin_amdgcn_mfma_f32_16x16x32_f16(af, sf, acc[ei], 0, 0, 0);
        }
        if (dt < 7) { writeBuf(cur ^ 1); cur ^= 1; }
    }

    // scale cross term rows
#pragma unroll
    for (int r = 0; r < 4; ++r) {
        int rp = mw * 16 + q4 + r;
        int rc = rp / 5;
        float rs = 0.f;
        if (rp < 125 && !(g == GSUP - 1 && rc == CSUP - 1)) rs = gpow((float)(6 * rc + 7));
#pragma unroll
        for (int ei = 0; ei < 4; ++ei) acc[ei][r] *= rs;
    }

    __syncthreads();   // all frag reads of staging buffers complete; safe to overlay

    // fill V^T tile from prefetched registers
    *(half8*)&VST(vm, vc << 3) = vtp[0];
    *(half8*)&VST(vm, (vc + 8) << 3) = vtp[1];
    // masked P -> LDS (fp16)
#pragma unroll
    for (int ci = 0; ci < 8; ++ci)
#pragma unroll
        for (int r = 0; r < 4; ++r) {
            int rp = mw * 16 + q4 + r;
            int cp = ci * 16 + ln;
            int rc = rp / 5, cc = cp / 5;
            float w = 0.f;
            if (rp < 125 && cp < 125 && cc <= rc && !(g == GSUP - 1 && rc == CSUP - 1))
                w = gpow((float)(6 * (rc - cc + 1)));
            PS(rp, cp) = (_Float16)(pacc[ci][r] * w);
        }
    __syncthreads();

    // PV: out += P @ V^T
#pragma unroll
    for (int ct = 0; ct < 4; ++ct) {
        int cp0 = ct * 32;
        half8 paf = *(const half8*)&PS(mw * 16 + ln, cp0 + q8);
#pragma unroll
        for (int ei = 0; ei < 4; ++ei) {
            half8 bv = *(const half8*)&VST(ei * 16 + ln, cp0 + q8);
            acc[ei] = __builtin_amdgcn_mfma_f32_16x16x32_f16(paf, bv, acc[ei], 0, 0, 0);
        }
    }

    // ---- epilogue: add intra term from scw + VST, single fp32 store
#pragma unroll
    for (int r = 0; r < 4; ++r) {
        int rp = mw * 16 + q4 + r;
        if (rp < 125) {
            int rc = rp / 5, pp = rp - rc * 5;
            const float* srow = scw + ((size_t)b * 800 + g * 25 + rc) * 25 + pp * 5;
            float a[4];
#pragma unroll
            for (int ei = 0; ei < 4; ++ei) a[ei] = acc[ei][r];
            for (int q = 0; q <= pp; ++q) {
                float s = srow[q];
#pragma unroll
                for (int ei = 0; ei < 4; ++ei)
                    a[ei] += s * (float)VST(ei * 16 + ln, rc * 5 + q);
            }
            size_t orow = ((size_t)b * SEQ + g * RPG + rp) * 256;
#pragma unroll
            for (int ei = 0; ei < 4; ++ei)
                out[orow + e0 + ei * 16 + ln] = a[ei];
        }
    }
}

extern "C" void kernel_launch(void* const* d_in, const int* in_sizes, int n_in,
                              void* d_out, int out_size, void* d_ws, size_t ws_size,
                              hipStream_t stream) {
    const float* xq = (const float*)d_in[0];
    const float* xk = (const float*)d_in[1];
    const float* xv = (const float*)d_in[2];
    const float* Wq = (const float*)d_in[3];
    const float* Wk = (const float*)d_in[4];
    const float* Wv = (const float*)d_in[5];
    float* out = (float*)d_out;

    const size_t NELEM = (size_t)SEQ * BATCH * 256;   // 8,192,000
    _Float16* Qb = (_Float16*)d_ws;
    _Float16* Kb = Qb + NELEM;
    _Float16* Vb = Kb + NELEM;
    _Float16* Wt = Vb + NELEM;                              // 196,608 halves
    _Float16* Wh = Wt + 196608;                             // [g][b][e][d] fp16, 33.5 MB
    _Float16* SprevT = Wh + (size_t)GSUP * BATCH * 65536;   // fp16, 33.5 MB
    float* scw = (float*)(SprevT + (size_t)GSUP * BATCH * 65536);  // 640 KB
    // VT (16.8 MB) reuses Wh's space: Wh is dead after state_scan.
    _Float16* VT = Wh;

    wt_convert<<<dim3(96), 256, 0, stream>>>(Wq, Wk, Wv, Wt);
    qkv_gemm_f16<<<dim3(250, 3), 256, 0, stream>>>(xq, xk, xv, Wt, Qb, Kb, Vb);
    chunk_states_mfma<<<dim3(2, 32, 8), 256, 0, stream>>>(Kb, Vb, Wh);
    state_scan<<<dim3(512), 256, 0, stream>>>(Wh, SprevT);
    vt_transpose<<<dim3(4, 32, 8), 256, 0, stream>>>(Vb, VT);
    intra_sc<<<dim3(200, 8), 256, 0, stream>>>(Qb, Kb, scw);
    cross_f16<<<dim3(4, 32, 8), 512, 0, stream>>>(Qb, Kb, VT, SprevT, scw, out);
}

// Round 9
// 242.747 us; speedup vs baseline: 1.0530x; 1.0530x over previous
//
#include <hip/hip_runtime.h>
#include <cmath>

#define GAMMA 0.9865f
#define L2G   -0.01960905f   // log2(0.9865)
#define BATCH 8
#define SEQ   4000
#define CSUP  25
#define GSUP  32
#define RPG   125            // rows per superchunk = 5*CSUP

typedef _Float16 half8 __attribute__((ext_vector_type(8)));
typedef _Float16 half4 __attribute__((ext_vector_type(4)));
typedef float    floatx4 __attribute__((ext_vector_type(4)));

__device__ __forceinline__ float gpow(float e) { return exp2f(e * L2G); }  // GAMMA^e

__device__ __forceinline__ void gl16(const void* g, void* l) {
    __builtin_amdgcn_global_load_lds(
        (const __attribute__((address_space(1))) void*)g,
        (__attribute__((address_space(3))) void*)l, 16, 0, 0);
}

// ---------------- Kernel 0: transpose+convert W -> Wt[mat][n][k] fp16 (R7 version)
__global__ __launch_bounds__(256) void wt_convert(
    const float* __restrict__ Wq, const float* __restrict__ Wk, const float* __restrict__ Wv,
    _Float16* __restrict__ Wt) {
    int t = blockIdx.x * 256 + threadIdx.x;           // 3*65536
    int mat = t >> 16, rem = t & 65535;
    int n = rem >> 8, k = rem & 255;
    const float* W = (mat == 0) ? Wq : (mat == 1) ? Wk : Wv;
    Wt[(size_t)mat * 65536 + n * 256 + k] = (_Float16)W[k * 256 + n];
}

// ---------------- Kernel 1: QKV projection, fp16 MFMA.  dst = x @ W  (M=32000,N=256,K=256)
// v9: global_load_lds DMA staging for X (fp32, swizzled source) and W (fp16, swizzled
// source); fp32->fp16 convert at fragment read; ONE barrier per K-step; no reg staging.
__global__ __launch_bounds__(256, 2) void qkv_gemm_f16(
    const float* __restrict__ xq, const float* __restrict__ xk, const float* __restrict__ xv,
    const _Float16* __restrict__ WtAll,
    _Float16* __restrict__ Qb, _Float16* __restrict__ Kb, _Float16* __restrict__ Vb) {
    int op = blockIdx.y;
    const float* x = (op == 0) ? xq : (op == 1) ? xk : xv;
    const _Float16* Wt = WtAll + (size_t)op * 65536;
    _Float16* dst = (op == 0) ? Qb : (op == 1) ? Kb : Vb;

    __shared__ __align__(16) float    XsF[2][128 * 32];   // 2 x 16 KB, XOR-swz chunks
    __shared__ __align__(16) _Float16 Ws[2][256 * 32];    // 2 x 16 KB, XOR-swz chunks

    int t = threadIdx.x;
    int lane = t & 63, wave = t >> 6;
    int ln = lane & 15, q8 = (lane >> 4) << 3, q4 = (lane >> 4) << 2;
    int row0 = blockIdx.x * 128;

    floatx4 acc[8][4] = {};

    auto stage = [&](int bf, int dt) {
        int k0 = dt * 32;
#pragma unroll
        for (int i = 0; i < 4; ++i) {                 // X: 128 rows x 8 chunks of 16B
            int idx = t + i * 256;                    // 0..1023
            int row = idx >> 3, p = idx & 7, c = p ^ (row & 7);
            gl16(&x[(size_t)(row0 + row) * 256 + k0 + c * 4],
                 (char*)&XsF[bf][0] + idx * 16);
        }
#pragma unroll
        for (int i = 0; i < 4; ++i) {                 // W: 256 rows x 4 chunks of 16B
            int idx = t + i * 256;
            int n = idx >> 2, p = idx & 3, c = p ^ ((n >> 1) & 3);
            gl16(&Wt[n * 256 + k0 + c * 8],
                 (char*)&Ws[bf][0] + idx * 16);
        }
    };

    stage(0, 0);
    __syncthreads();
    int cur = 0;
    for (int dt = 0; dt < 8; ++dt) {
        if (dt < 7) stage(cur ^ 1, dt + 1);           // DMA into other buffer, in flight
        half8 af[8];
#pragma unroll
        for (int mi = 0; mi < 8; ++mi) {              // fp32 frag + convert
            int row = mi * 16 + ln;
            int s = ln & 7, c0 = q8 >> 2;             // c0 in {0,2,4,6}
            const float* base = &XsF[cur][row * 32];
            floatx4 v0 = *(const floatx4*)&base[(c0 ^ s) << 2];
            floatx4 v1 = *(const floatx4*)&base[((c0 + 1) ^ s) << 2];
            half8 h;
            h[0] = (_Float16)v0[0]; h[1] = (_Float16)v0[1];
            h[2] = (_Float16)v0[2]; h[3] = (_Float16)v0[3];
            h[4] = (_Float16)v1[0]; h[5] = (_Float16)v1[1];
            h[6] = (_Float16)v1[2]; h[7] = (_Float16)v1[3];
            af[mi] = h;
        }
#pragma unroll
        for (int ni = 0; ni < 4; ++ni) {
            int n = (wave * 4 + ni) * 16 + ln;
            int p = (q8 >> 3) ^ ((n >> 1) & 3);
            half8 bf = *(const half8*)&Ws[cur][n * 32 + p * 8];
#pragma unroll
            for (int mi = 0; mi < 8; ++mi)
                acc[mi][ni] = __builtin_amdgcn_mfma_f32_16x16x32_f16(af[mi], bf, acc[mi][ni], 0, 0, 0);
        }
        __syncthreads();                              // drains this iter's DMA + LDS reads
        cur ^= 1;
    }
#pragma unroll
    for (int mi = 0; mi < 8; ++mi)
#pragma unroll
        for (int ni = 0; ni < 4; ++ni)
#pragma unroll
            for (int r = 0; r < 4; ++r) {
                int row = row0 + mi * 16 + q4 + r;
                int col = (wave * 4 + ni) * 16 + ln;
                dst[(size_t)row * 256 + col] = (_Float16)acc[mi][ni][r];
            }
}

// ---------------- Kernel 1b: V transpose into padded VT[b][e][g][128] (fp16, zeros for cp>=125).
__global__ __launch_bounds__(256) void vt_transpose(
    const _Float16* __restrict__ Vb, _Float16* __restrict__ VT) {
    int es = blockIdx.x, g = blockIdx.y, b = blockIdx.z;
    int t = threadIdx.x;
    __shared__ __align__(16) _Float16 Ls[64 * 136];
    // logical Ls[e][cp], physical: e*136 + (((cp>>3) ^ (e>>3))<<3) + (cp&7)
#pragma unroll
    for (int i = 0; i < 4; ++i) {
        int idx = t + i * 256;
        int cp = idx >> 3, eg = idx & 7;
        half8 v = {};
        if (cp < 125)
            v = *(const half8*)&Vb[((size_t)b * SEQ + g * RPG + cp) * 256 + es * 64 + eg * 8];
        int cpg = cp >> 3, c7 = cp & 7;
#pragma unroll
        for (int z = 0; z < 8; ++z) {
            int e = eg * 8 + z;
            Ls[e * 136 + ((cpg ^ (e >> 3)) << 3) + c7] = v[z];
        }
    }
    __syncthreads();
#pragma unroll
    for (int jj = 0; jj < 4; ++jj) {
        int ee = jj * 16 + (t >> 4);
        int cpg = t & 15;
        half8 h = *(const half8*)&Ls[ee * 136 + ((cpg ^ (ee >> 3)) << 3)];
        *(half8*)&VT[(((size_t)b * 256 + es * 64 + ee) * 32 + g) * 128 + cpg * 8] = h;
    }
}

// ---------------- Kernel 2: chunk states via MFMA (R7-verified: transposed swizzled staging).
__global__ __launch_bounds__(256, 2) void chunk_states_mfma(
    const _Float16* __restrict__ Kb, const _Float16* __restrict__ Vb,
    _Float16* __restrict__ Wh) {
    int lin = blockIdx.x + 2 * (blockIdx.y + 32 * blockIdx.z);   // 0..511
    int swz = (lin & 7) * 64 + (lin >> 3);
    int eh = swz & 1, g = (swz >> 1) & 31, b = swz >> 6;

    int t = threadIdx.x, lane = t & 63, wave = t >> 6;
    int ln = lane & 15, q8 = (lane >> 4) << 3, q4 = (lane >> 4) << 2;
    __shared__ __align__(16) _Float16 VsT[128 * 40];   // [e][r]
    __shared__ __align__(16) _Float16 KsT[256 * 40];   // [d][r]
    size_t base_row = (size_t)b * SEQ + g * RPG;
    floatx4 acc[8][4] = {};
    int rb = q8 >> 3;                                  // k-block index 0..3
    for (int kt = 0; kt < 4; ++kt) {
        int r0 = kt * 32;
#pragma unroll
        for (int i = 0; i < 2; ++i) {          // V^T stage with alpha: 8 e's at fixed r
            int idx = t + i * 256;
            int r = idx >> 4, e8 = (idx & 15) << 3;
            half8 v = {};
            if (r0 + r < RPG) {
                v = *(const half8*)&Vb[(base_row + r0 + r) * 256 + eh * 128 + e8];
                int mloc = (r0 + r) / 5;
                float a = gpow((float)(149 - 6 * mloc));
#pragma unroll
                for (int z = 0; z < 8; ++z) v[z] = (_Float16)((float)v[z] * a);
            }
            int base = e8 * 40 + ((((r >> 3) ^ ((e8 >> 3) & 3))) << 3) + (r & 7);
#pragma unroll
            for (int z = 0; z < 8; ++z) VsT[base + z * 40] = v[z];
        }
#pragma unroll
        for (int i = 0; i < 4; ++i) {          // K^T stage: 8 d's at fixed r
            int idx = t + i * 256;
            int r = idx >> 5, d8 = (idx & 31) << 3;
            half8 v = {};
            if (r0 + r < RPG) v = *(const half8*)&Kb[(base_row + r0 + r) * 256 + d8];
            int base = d8 * 40 + ((((r >> 3) ^ ((d8 >> 3) & 3))) << 3) + (r & 7);
#pragma unroll
            for (int z = 0; z < 8; ++z) KsT[base + z * 40] = v[z];
        }
        __syncthreads();
        half8 Af[8], Bf[4];
#pragma unroll
        for (int mi = 0; mi < 8; ++mi) {
            int e = mi * 16 + ln;
            Af[mi] = *(const half8*)&VsT[e * 40 + ((rb ^ ((e >> 3) & 3)) << 3)];
        }
#pragma unroll
        for (int ni = 0; ni < 4; ++ni) {
            int d = wave * 64 + ni * 16 + ln;
            Bf[ni] = *(const half8*)&KsT[d * 40 + ((rb ^ ((d >> 3) & 3)) << 3)];
        }
#pragma unroll
        for (int mi = 0; mi < 8; ++mi)
#pragma unroll
            for (int ni = 0; ni < 4; ++ni)
                acc[mi][ni] = __builtin_amdgcn_mfma_f32_16x16x32_f16(Af[mi], Bf[ni], acc[mi][ni], 0, 0, 0);
        __syncthreads();
    }
    size_t ob = ((size_t)(g * 8 + b)) << 16;
#pragma unroll
    for (int mi = 0; mi < 8; ++mi)
#pragma unroll
        for (int ni = 0; ni < 4; ++ni)
#pragma unroll
            for (int r = 0; r < 4; ++r) {
                int e = eh * 128 + mi * 16 + q4 + r;
                int d = wave * 64 + ni * 16 + ln;
                Wh[ob + (size_t)e * 256 + d] = (_Float16)acc[mi][ni][r];
            }
}

// ---------------- Kernel 3: exclusive scan over g (fp16 in/out, fp32 accum)
__global__ __launch_bounds__(256) void state_scan(
    const _Float16* __restrict__ Wh, _Float16* __restrict__ SprevT) {
    int t = blockIdx.x * 256 + threadIdx.x;   // 131072 threads
    int b = t >> 14;
    int idx = (t & 16383) << 2;               // 4 consecutive halves
    const float gF = gpow(150.0f);
    float s[4] = {};
    half4 w = *(const half4*)&Wh[(((size_t)b) << 16) + idx];
    for (int g = 0; g < GSUP; ++g) {
        size_t o = (((size_t)(g * 8 + b)) << 16) + idx;
        half4 wn = {};
        if (g < GSUP - 1) wn = *(const half4*)&Wh[o + (8ull << 16)];
        half4 sv;
#pragma unroll
        for (int z = 0; z < 4; ++z) { sv[z] = (_Float16)s[z]; s[z] = (float)w[z] + gF * s[z]; }
        *(half4*)&SprevT[o] = sv;
        w = wn;
    }
}

// ---------------- Kernel 4: intra score matrices, pre-scaled by gamma^(q-p).
__global__ __launch_bounds__(256) void intra_sc(
    const _Float16* __restrict__ Qb, const _Float16* __restrict__ Kb, float* __restrict__ scw) {
    int b = blockIdx.y;
    int j = blockIdx.x * 4 + (threadIdx.x >> 6);
    int lane = threadIdx.x & 63;
    size_t base = ((size_t)b * SEQ + j * 5) * 256 + lane * 4;
    half4 qv[5], kv[5];
#pragma unroll
    for (int p = 0; p < 5; ++p) {
        qv[p] = *(const half4*)&Qb[base + p * 256];
        kv[p] = *(const half4*)&Kb[base + p * 256];
    }
#pragma unroll
    for (int p = 0; p < 5; ++p)
#pragma unroll
        for (int q = 0; q <= p; ++q) {
            float s = 0.f;
#pragma unroll
            for (int z = 0; z < 4; ++z) s += (float)qv[p][z] * (float)kv[q][z];
#pragma unroll
            for (int off = 32; off; off >>= 1) s += __shfl_xor(s, off, 64);
            if (lane == 0) scw[((size_t)b * 800 + j) * 25 + p * 5 + q] = s * gpow((float)(q - p));
        }
}

// ---------------- Kernel 5: cross + fused intra epilogue (R7-verified).
__global__ __launch_bounds__(512, 2) void cross_f16(
    const _Float16* __restrict__ Qb, const _Float16* __restrict__ Kb,
    const _Float16* __restrict__ VT, const _Float16* __restrict__ SprevT,
    const float* __restrict__ scw, float* __restrict__ out) {
    int lin = blockIdx.x + 4 * (blockIdx.y + 32 * blockIdx.z);   // 0..1023
    int swz = (lin & 7) * 128 + (lin >> 3);
    int eq = swz & 3, g = (swz >> 2) & 31, b = swz >> 7;
    int e0 = eq * 64;
    int t = threadIdx.x;
    int lane = t & 63, wave = t >> 6;          // 8 waves
    int ln = lane & 15, q8 = (lane >> 4) << 3, q4 = (lane >> 4) << 2;
    int mw = wave;                             // m-tile index 0..7

    __shared__ __align__(16) char smem[52224];
    _Float16* QsB  = (_Float16*)smem;              // [2][128][40] = 20480 B
    _Float16* KsB  = (_Float16*)(smem + 20480);    // [2][128][40] = 20480 B
    _Float16* SsB  = (_Float16*)(smem + 40960);    // [2][64][40]  = 10240 B
    _Float16* VsTB = (_Float16*)smem;              // [64][136] (phase 2)
    _Float16* PsB  = (_Float16*)(smem + 17408);    // [128][136] (phase 2)
#define QS(bf_, m_, k_)  QsB[(bf_) * 5120 + (m_) * 40 + (k_)]
#define KS(bf_, m_, k_)  KsB[(bf_) * 5120 + (m_) * 40 + (k_)]
#define SS(bf_, m_, k_)  SsB[(bf_) * 2560 + (m_) * 40 + (k_)]
#define PS(m_, k_)  PsB[(m_) * 136 + (k_)]
#define VST(m_, k_) VsTB[(m_) * 136 + (k_)]

    size_t kvbase = (size_t)b * SEQ + g * RPG;
    size_t sb = ((size_t)(g * 8 + b)) << 16;

    int qm = t >> 2, qk = (t & 3) << 3;   // staging: Q/K row 0..127, col chunk 0..3
    int vm = t >> 3, vc = t & 7;          // VT: row 0..63, chunks vc, vc+8

    floatx4 pacc[8] = {};
    floatx4 acc[4] = {};
    half8 qn, kn, sn;
    half8 vtp[2];

    auto loadNext = [&](int dt) {
        int d0 = dt * 32;
        half8 z = {};
        int qr = g * RPG + 5 + qm;
        qn = z;
        if (qm < 125 && qr < SEQ) qn = *(const half8*)&Qb[((size_t)b * SEQ + qr) * 256 + d0 + qk];
        kn = z;
        if (qm < 125) kn = *(const half8*)&Kb[(kvbase + qm) * 256 + d0 + qk];
        if (t < 256) sn = *(const half8*)&SprevT[sb + (size_t)(e0 + (t >> 2)) * 256 + d0 + qk];
    };
    auto writeBuf = [&](int bf) {
        *(half8*)&QS(bf, qm, qk) = qn;
        *(half8*)&KS(bf, qm, qk) = kn;
        if (t < 256) *(half8*)&SS(bf, t >> 2, qk) = sn;
    };

    loadNext(0); writeBuf(0);
    int cur = 0;
    for (int dt = 0; dt < 8; ++dt) {
        __syncthreads();
        if (dt < 7) loadNext(dt + 1);
        if (dt == 7) {
            size_t vtbase = (((size_t)b * 256 + e0 + vm) * 32 + g) * 128;
            vtp[0] = *(const half8*)&VT[vtbase + vc * 8];
            vtp[1] = *(const half8*)&VT[vtbase + (vc + 8) * 8];
        }
        half8 af = *(const half8*)&QS(cur, mw * 16 + ln, q8);
#pragma unroll
        for (int ci = 0; ci < 8; ++ci) {
            half8 bf = *(const half8*)&KS(cur, ci * 16 + ln, q8);
            pacc[ci] = __builtin_amdgcn_mfma_f32_16x16x32_f16(af, bf, pacc[ci], 0, 0, 0);
        }
#pragma unroll
        for (int ei = 0; ei < 4; ++ei) {
            half8 sf = *(const half8*)&SS(cur, ei * 16 + ln, q8);
            acc[ei] = __builtin_amdgcn_mfma_f32_16x16x32_f16(af, sf, acc[ei], 0, 0, 0);
        }
        if (dt < 7) { writeBuf(cur ^ 1); cur ^= 1; }
    }

    // scale cross term rows
#pragma unroll
    for (int r = 0; r < 4; ++r) {
        int rp = mw * 16 + q4 + r;
        int rc = rp / 5;
        float rs = 0.f;
        if (rp < 125 && !(g == GSUP - 1 && rc == CSUP - 1)) rs = gpow((float)(6 * rc + 7));
#pragma unroll
        for (int ei = 0; ei < 4; ++ei) acc[ei][r] *= rs;
    }

    __syncthreads();   // all frag reads of staging buffers complete; safe to overlay

    // fill V^T tile from prefetched registers
    *(half8*)&VST(vm, vc << 3) = vtp[0];
    *(half8*)&VST(vm, (vc + 8) << 3) = vtp[1];
    // masked P -> LDS (fp16)
#pragma unroll
    for (int ci = 0; ci < 8; ++ci)
#pragma unroll
        for (int r = 0; r < 4; ++r) {
            int rp = mw * 16 + q4 + r;
            int cp = ci * 16 + ln;
            int rc = rp / 5, cc = cp / 5;
            float w = 0.f;
            if (rp < 125 && cp < 125 && cc <= rc && !(g == GSUP - 1 && rc == CSUP - 1))
                w = gpow((float)(6 * (rc - cc + 1)));
            PS(rp, cp) = (_Float16)(pacc[ci][r] * w);
        }
    __syncthreads();

    // PV: out += P @ V^T
#pragma unroll
    for (int ct = 0; ct < 4; ++ct) {
        int cp0 = ct * 32;
        half8 paf = *(const half8*)&PS(mw * 16 + ln, cp0 + q8);
#pragma unroll
        for (int ei = 0; ei < 4; ++ei) {
            half8 bv = *(const half8*)&VST(ei * 16 + ln, cp0 + q8);
            acc[ei] = __builtin_amdgcn_mfma_f32_16x16x32_f16(paf, bv, acc[ei], 0, 0, 0);
        }
    }

    // ---- epilogue: add intra term from scw + VST, single fp32 store
#pragma unroll
    for (int r = 0; r < 4; ++r) {
        int rp = mw * 16 + q4 + r;
        if (rp < 125) {
            int rc = rp / 5, pp = rp - rc * 5;
            const float* srow = scw + ((size_t)b * 800 + g * 25 + rc) * 25 + pp * 5;
            float a[4];
#pragma unroll
            for (int ei = 0; ei < 4; ++ei) a[ei] = acc[ei][r];
            for (int q = 0; q <= pp; ++q) {
                float s = srow[q];
#pragma unroll
                for (int ei = 0; ei < 4; ++ei)
                    a[ei] += s * (float)VST(ei * 16 + ln, rc * 5 + q);
            }
            size_t orow = ((size_t)b * SEQ + g * RPG + rp) * 256;
#pragma unroll
            for (int ei = 0; ei < 4; ++ei)
                out[orow + e0 + ei * 16 + ln] = a[ei];
        }
    }
}

extern "C" void kernel_launch(void* const* d_in, const int* in_sizes, int n_in,
                              void* d_out, int out_size, void* d_ws, size_t ws_size,
                              hipStream_t stream) {
    const float* xq = (const float*)d_in[0];
    const float* xk = (const float*)d_in[1];
    const float* xv = (const float*)d_in[2];
    const float* Wq = (const float*)d_in[3];
    const float* Wk = (const float*)d_in[4];
    const float* Wv = (const float*)d_in[5];
    float* out = (float*)d_out;

    const size_t NELEM = (size_t)SEQ * BATCH * 256;   // 8,192,000
    _Float16* Qb = (_Float16*)d_ws;
    _Float16* Kb = Qb + NELEM;
    _Float16* Vb = Kb + NELEM;
    _Float16* Wt = Vb + NELEM;                              // 196,608 halves
    _Float16* Wh = Wt + 196608;                             // [g][b][e][d] fp16, 33.5 MB
    _Float16* SprevT = Wh + (size_t)GSUP * BATCH * 65536;   // fp16, 33.5 MB
    float* scw = (float*)(SprevT + (size_t)GSUP * BATCH * 65536);  // 640 KB
    // VT (16.8 MB) reuses Wh's space: Wh is dead after state_scan.
    _Float16* VT = Wh;

    wt_convert<<<dim3(768), 256, 0, stream>>>(Wq, Wk, Wv, Wt);
    qkv_gemm_f16<<<dim3(250, 3), 256, 0, stream>>>(xq, xk, xv, Wt, Qb, Kb, Vb);
    chunk_states_mfma<<<dim3(2, 32, 8), 256, 0, stream>>>(Kb, Vb, Wh);
    state_scan<<<dim3(512), 256, 0, stream>>>(Wh, SprevT);
    vt_transpose<<<dim3(4, 32, 8), 256, 0, stream>>>(Vb, VT);
    intra_sc<<<dim3(200, 8), 256, 0, stream>>>(Qb, Kb, scw);
    cross_f16<<<dim3(4, 32, 8), 512, 0, stream>>>(Qb, Kb, VT, SprevT, scw, out);
}